// Round 6
// baseline (146747.986 us; speedup 1.0000x reference)
//
#include <hip/hip_runtime.h>
#include <stdint.h>

typedef unsigned int uint32;
typedef unsigned long long uint64;

#define T_SEQ 8192
#define NWG_L 128

// LDS byte offsets
#define OFF_WIH0  65536            // L0 only: Wih0 32x608B
#define OFF_BIAS  131072           // f32 [32]
#define LDS_BYTES 131200

// ---------------- device helpers ----------------
__device__ __forceinline__ float bflo(uint32 u){ return __uint_as_float(u << 16); }
__device__ __forceinline__ float bfhi(uint32 u){ return __uint_as_float(u & 0xffff0000u); }

__device__ __forceinline__ unsigned short f2bf(float f){
  uint32 u = __float_as_uint(f);
  u += 0x7fffu + ((u >> 16) & 1u);          // round-to-nearest-even
  return (unsigned short)(u >> 16);
}

__device__ __forceinline__ void mac8(float& a, uint4 w,
    float h0,float h1,float h2,float h3,float h4,float h5,float h6,float h7){
  a = fmaf(bflo(w.x), h0, a); a = fmaf(bfhi(w.x), h1, a);
  a = fmaf(bflo(w.y), h2, a); a = fmaf(bfhi(w.y), h3, a);
  a = fmaf(bflo(w.z), h4, a); a = fmaf(bfhi(w.z), h5, a);
  a = fmaf(bflo(w.w), h6, a); a = fmaf(bfhi(w.w), h7, a);
}

__device__ __forceinline__ uint64 ald64(const uint64* p){
  return __hip_atomic_load(p, __ATOMIC_RELAXED, __HIP_MEMORY_SCOPE_AGENT);
}
__device__ __forceinline__ void ast64(uint64* p, uint64 v){
  __hip_atomic_store(p, v, __ATOMIC_RELAXED, __HIP_MEMORY_SCOPE_AGENT);
}
__device__ __forceinline__ uint32 ald32(const uint32* p){
  return __hip_atomic_load(p, __ATOMIC_RELAXED, __HIP_MEMORY_SCOPE_AGENT);
}
__device__ __forceinline__ void ast32(uint32* p, uint32 v){
  __hip_atomic_store(p, v, __ATOMIC_RELAXED, __HIP_MEMORY_SCOPE_AGENT);
}
__device__ __forceinline__ float val_of(uint64 w){ return __uint_as_float((uint32)(w >> 32)); }

// Poll 32 sub-counter lines (lane c -> counter c&31) until all >= tgt. Relaxed;
// correctness is enforced downstream by data tags (self-healing).
__device__ __forceinline__ void cnt_wait(const uint32* cnt, int c, uint32 tgt){
  uint32 guard = 0;
  for (;;) {
    uint32 v = ald32(cnt + (size_t)(c & 31) * 64);
    if (__all(v >= tgt)) break;
    __builtin_amdgcn_s_sleep(1);
    if (++guard > 20000000u) break;        // bug -> garbage, not hang
  }
}

// ---------------- persistent 2-layer LSTM ----------------
// 256 WGs x 256 thr (1 WG/CU). WG 0..127: layer0 (8 units); 128..255: layer1.
// Wave wv owns units 2wv,2wv+1 (rows g*8+2wv+j): in-wave butterfly + lane-uniform
// gates; NO barriers in the step loop. Ring word for unit u at spread(u)=
// ((u&15)<<6)|(u>>4), value (fp32(h)<<32)|(t+1), one relaxed agent 8B atomic.
// NOTIFY: 32 sub-counters/layer (256B apart). Producer wave: tagged stores, then
// ONE fetch_add(RELEASE) (vmcnt-drains stores). Consumers: issue data loads early,
// fast-path tag check; on miss poll ONLY counter lines (2KB/round, disjoint from
// data lines -> no hot-line storm), then reload data once + tag-verify loop.
// h1 ring 16 deep, h2 ring 4 deep; L0 overwrite gated by prog >= t-12.
extern "C" __global__ void __launch_bounds__(256)
lstm_persistent(const float* __restrict__ quote,
                const float* __restrict__ Wih0, const float* __restrict__ Whh0,
                const float* __restrict__ bih0, const float* __restrict__ bhh0,
                const float* __restrict__ Wih1, const float* __restrict__ Whh1,
                const float* __restrict__ bih1, const float* __restrict__ bhh1,
                uint64* __restrict__ h1r, uint64* __restrict__ h2r,
                uint32* __restrict__ cnt1, uint32* __restrict__ cnt2,
                uint32* __restrict__ prog, float* __restrict__ h2last)
{
  extern __shared__ char smem[];
  float* biasL = (float*)(smem + OFF_BIAS);

  const int tid = threadIdx.x;
  const int wv  = tid >> 6;          // 0..3
  const int c   = tid & 63;
  const int wg  = blockIdx.x;
  const bool isL1 = (wg >= NWG_L);
  const int lwg = isL1 ? (wg - NWG_L) : wg;
  const int unit_base = lwg * 8;
  const int ci = ((lwg & 7) << 2) | wv;   // sub-counter index (16 adds/step each)

  // ---- one-time weight fill: fp32 global -> bf16 LDS (piece-interleaved) ----
  if (!isL1) {
    for (int gi = tid; gi < 4096; gi += 256) {           // Whh0: 32 rows x 128 groups
      int r  = gi >> 7;
      int x0 = (gi & 127) << 3;
      int R  = (r >> 3) * 1024 + unit_base + (r & 7);
      const float* s = Whh0 + (size_t)R * 1024 + x0;
      unsigned short* d = (unsigned short*)(smem + r*2048 + ((x0>>3)&1)*1024 + (x0>>4)*16);
      #pragma unroll
      for (int m = 0; m < 8; ++m) d[m] = f2bf(s[m]);
    }
    for (int gi = tid; gi < 1216; gi += 256) {           // Wih0: 32 rows x 38 groups
      int r  = gi / 38;
      int g  = gi - r * 38;
      int x0 = g << 3;
      int R  = (r >> 3) * 1024 + unit_base + (r & 7);
      unsigned short* d = (unsigned short*)(smem + OFF_WIH0 + r*608 + x0*2);
      #pragma unroll
      for (int m = 0; m < 8; ++m) {
        int x = x0 + m;
        d[m] = f2bf(x < 300 ? Wih0[(size_t)R * 300 + x] : 0.0f);
      }
    }
    if (tid < 32) {
      int R = (tid >> 3) * 1024 + unit_base + (tid & 7);
      biasL[tid] = bih0[R] + bhh0[R];
    }
  } else {
    for (int gi = tid; gi < 8192; gi += 256) {           // concat: 32 rows x 256 groups
      int r  = gi >> 8;
      int x0 = (gi & 255) << 3;                          // concat col 0..2047
      int R  = (r >> 3) * 1024 + unit_base + (r & 7);
      const float* s = (x0 < 1024) ? (Wih1 + (size_t)R*1024 + x0)
                                   : (Whh1 + (size_t)R*1024 + (x0 - 1024));
      int p  = x0 >> 9;
      int cs = (x0 & 511) >> 3;
      unsigned short* d = (unsigned short*)(smem + r*4096 + p*1024 + cs*16);
      #pragma unroll
      for (int m = 0; m < 8; ++m) d[m] = f2bf(s[m]);
    }
    if (tid < 32) {
      int R = (tid >> 3) * 1024 + unit_base + (tid & 7);
      biasL[tid] = bih1[R] + bhh1[R];
    }
  }
  __syncthreads();

  // per-wave biases for rows g*8 + 2wv + {0,1} (lane-uniform scalars)
  float bA0 = biasL[0*8+2*wv],   bA1 = biasL[1*8+2*wv],
        bA2 = biasL[2*8+2*wv],   bA3 = biasL[3*8+2*wv];
  float bB0 = biasL[0*8+2*wv+1], bB1 = biasL[1*8+2*wv+1],
        bB2 = biasL[2*8+2*wv+1], bB3 = biasL[3*8+2*wv+1];

  float cstA = 0.0f, cstB = 0.0f;
  uint32 prog_seen = 0;

  for (int t = 0; t < T_SEQ; ++t) {
    float acc[8];
    #pragma unroll
    for (int i = 0; i < 8; ++i) acc[i] = 0.0f;

    if (!isL1) {
      // ---- issue h1[t-1] loads early (coalesced: ring[k*64+c] == h[c*16+k]) ----
      uint64 up[16];
      const uint64* hb = h1r + (size_t)((t-1) & 15) * 1024;
      if (t > 0) {
        #pragma unroll
        for (int k = 0; k < 16; ++k) up[k] = ald64(hb + (k << 6) + c);
      }
      // ---- x-part (independent of recurrence; hides data-load latency) ----
      if (c < 38) {
        float xv[8];
        int x0 = c << 3;
        const float* xr = quote + (size_t)t * 300 + x0;
        #pragma unroll
        for (int m = 0; m < 8; ++m) xv[m] = (x0 + m < 300) ? xr[m] : 0.0f;
        #pragma unroll
        for (int g = 0; g < 4; ++g)
          #pragma unroll
          for (int j = 0; j < 2; ++j) {
            int r = g*8 + 2*wv + j;
            uint4 w = *(const uint4*)(smem + OFF_WIH0 + r*608 + (c << 4));
            mac8(acc[g*2+j], w, xv[0],xv[1],xv[2],xv[3],xv[4],xv[5],xv[6],xv[7]);
          }
      }
      if (t > 0) {
        const uint32 want = (uint32)t;
        bool ok = true;
        #pragma unroll
        for (int k = 0; k < 16; ++k) ok &= ((uint32)up[k] == want);
        if (!__all(ok)) {
          cnt_wait(cnt1, c, 16u * (uint32)t);            // notify surface only
          uint32 guard = 0;
          for (;;) {                                      // one reload + verify
            #pragma unroll
            for (int k = 0; k < 16; ++k) up[k] = ald64(hb + (k << 6) + c);
            bool ok2 = true;
            #pragma unroll
            for (int k = 0; k < 16; ++k) ok2 &= ((uint32)up[k] == want);
            if (__all(ok2)) break;
            __builtin_amdgcn_s_sleep(1);
            if (++guard > 2000000u) break;
          }
        }
        #pragma unroll
        for (int g = 0; g < 4; ++g)
          #pragma unroll
          for (int j = 0; j < 2; ++j) {
            int r = g*8 + 2*wv + j;
            const char* rowb = smem + r*2048;
            uint4 w0 = *(const uint4*)(rowb + (c << 4));
            uint4 w1 = *(const uint4*)(rowb + 1024 + (c << 4));
            mac8(acc[g*2+j], w0, val_of(up[0]),val_of(up[1]),val_of(up[2]),val_of(up[3]),
                              val_of(up[4]),val_of(up[5]),val_of(up[6]),val_of(up[7]));
            mac8(acc[g*2+j], w1, val_of(up[8]),val_of(up[9]),val_of(up[10]),val_of(up[11]),
                              val_of(up[12]),val_of(up[13]),val_of(up[14]),val_of(up[15]));
          }
      }
    } else {
      // Lane c needs h[c*8+k], h[512+c*8+k]: ring idx vbase+k*64, +32.
      const int vbase = ((c & 1) << 9) + (c >> 1);
      uint64 ua[16], ub[16];
      const uint64* h2b = h2r + (size_t)((t-1) & 3) * 1024;
      const uint64* h1b = h1r + (size_t)(t & 15) * 1024;
      if (t > 0) {
        #pragma unroll
        for (int k = 0; k < 8; ++k) {
          ua[k]   = ald64(h2b + vbase + (k << 6));
          ua[8+k] = ald64(h2b + vbase + (k << 6) + 32);
        }
      }
      #pragma unroll
      for (int k = 0; k < 8; ++k) {
        ub[k]   = ald64(h1b + vbase + (k << 6));
        ub[8+k] = ald64(h1b + vbase + (k << 6) + 32);
      }

      // ---- phase B first: Wih1 * h1[t] (L0 usually ahead -> fast path) ----
      {
        const uint32 want = (uint32)(t + 1);
        bool ok = true;
        #pragma unroll
        for (int k = 0; k < 16; ++k) ok &= ((uint32)ub[k] == want);
        if (!__all(ok)) {
          cnt_wait(cnt1, c, 16u * (uint32)(t + 1));
          uint32 guard = 0;
          for (;;) {
            #pragma unroll
            for (int k = 0; k < 8; ++k) {
              ub[k]   = ald64(h1b + vbase + (k << 6));
              ub[8+k] = ald64(h1b + vbase + (k << 6) + 32);
            }
            bool ok2 = true;
            #pragma unroll
            for (int k = 0; k < 16; ++k) ok2 &= ((uint32)ub[k] == want);
            if (__all(ok2)) break;
            __builtin_amdgcn_s_sleep(1);
            if (++guard > 2000000u) break;
          }
        }
        #pragma unroll
        for (int g = 0; g < 4; ++g)
          #pragma unroll
          for (int j = 0; j < 2; ++j) {
            int r = g*8 + 2*wv + j;
            const char* rowb = smem + r*4096;
            uint4 w0 = *(const uint4*)(rowb + (c << 4));
            uint4 w1 = *(const uint4*)(rowb + 1024 + (c << 4));
            mac8(acc[g*2+j], w0, val_of(ub[0]),val_of(ub[1]),val_of(ub[2]),val_of(ub[3]),
                              val_of(ub[4]),val_of(ub[5]),val_of(ub[6]),val_of(ub[7]));
            mac8(acc[g*2+j], w1, val_of(ub[8]),val_of(ub[9]),val_of(ub[10]),val_of(ub[11]),
                              val_of(ub[12]),val_of(ub[13]),val_of(ub[14]),val_of(ub[15]));
          }
      }
      // ---- phase A: Whh1 * h2[t-1] (self-layer pace-setter) ----
      if (t > 0) {
        const uint32 want = (uint32)t;
        bool ok = true;
        #pragma unroll
        for (int k = 0; k < 16; ++k) ok &= ((uint32)ua[k] == want);
        if (!__all(ok)) {
          cnt_wait(cnt2, c, 16u * (uint32)t);
          uint32 guard = 0;
          for (;;) {
            #pragma unroll
            for (int k = 0; k < 8; ++k) {
              ua[k]   = ald64(h2b + vbase + (k << 6));
              ua[8+k] = ald64(h2b + vbase + (k << 6) + 32);
            }
            bool ok2 = true;
            #pragma unroll
            for (int k = 0; k < 16; ++k) ok2 &= ((uint32)ua[k] == want);
            if (__all(ok2)) break;
            __builtin_amdgcn_s_sleep(1);
            if (++guard > 2000000u) break;
          }
        }
        #pragma unroll
        for (int g = 0; g < 4; ++g)
          #pragma unroll
          for (int j = 0; j < 2; ++j) {
            int r = g*8 + 2*wv + j;
            const char* rowb = smem + r*4096;
            uint4 w2 = *(const uint4*)(rowb + 2048 + (c << 4));
            uint4 w3 = *(const uint4*)(rowb + 3072 + (c << 4));
            mac8(acc[g*2+j], w2, val_of(ua[0]),val_of(ua[1]),val_of(ua[2]),val_of(ua[3]),
                              val_of(ua[4]),val_of(ua[5]),val_of(ua[6]),val_of(ua[7]));
            mac8(acc[g*2+j], w3, val_of(ua[8]),val_of(ua[9]),val_of(ua[10]),val_of(ua[11]),
                              val_of(ua[12]),val_of(ua[13]),val_of(ua[14]),val_of(ua[15]));
          }
      }
    }

    // ---- full butterfly: every lane ends with all 8 row totals ----
    #pragma unroll
    for (int i = 0; i < 8; ++i) {
      #pragma unroll
      for (int m = 1; m < 64; m <<= 1) acc[i] += __shfl_xor(acc[i], m);
    }
    // ---- gates (lane-uniform), units A=2wv, B=2wv+1 ----
    float gA0 = acc[0] + bA0, gA1 = acc[2] + bA1, gA2 = acc[4] + bA2, gA3 = acc[6] + bA3;
    float iA = 1.0f/(1.0f+expf(-gA0)), fA = 1.0f/(1.0f+expf(-gA1));
    float gA = tanhf(gA2),             oA = 1.0f/(1.0f+expf(-gA3));
    cstA = fA*cstA + iA*gA;
    float hA = oA * tanhf(cstA);
    float gB0 = acc[1] + bB0, gB1 = acc[3] + bB1, gB2 = acc[5] + bB2, gB3 = acc[7] + bB3;
    float iB = 1.0f/(1.0f+expf(-gB0)), fB = 1.0f/(1.0f+expf(-gB1));
    float gB = tanhf(gB2),             oB = 1.0f/(1.0f+expf(-gB3));
    cstB = fB*cstB + iB*gB;
    float hB = oB * tanhf(cstB);

    // ---- publish (lanes 0,1), then ONE release-add notifies (drains stores) ----
    if (!isL1) {
      if ((int)prog_seen < t - 12) {       // ring back-pressure (rarely taken)
        uint32 guard = 0;
        for (;;) {
          uint32 p = ald32(prog);
          if ((int)p >= t - 12) { prog_seen = p; break; }
          __builtin_amdgcn_s_sleep(2);
          if (++guard > 20000000u) break;
        }
      }
      if (c < 2) {
        int u = unit_base + 2*wv + c;
        int v = ((u & 15) << 6) | (u >> 4);
        float h = c ? hB : hA;
        ast64(h1r + (size_t)(t & 15) * 1024 + v,
              ((uint64)__float_as_uint(h) << 32) | (uint32)(t + 1));
      }
      if (c == 0)
        __hip_atomic_fetch_add(cnt1 + (size_t)ci * 64, 1u,
                               __ATOMIC_RELEASE, __HIP_MEMORY_SCOPE_AGENT);
    } else {
      if (c < 2) {
        int u = unit_base + 2*wv + c;
        int v = ((u & 15) << 6) | (u >> 4);
        float h = c ? hB : hA;
        ast64(h2r + (size_t)(t & 3) * 1024 + v,
              ((uint64)__float_as_uint(h) << 32) | (uint32)(t + 1));
        if (t == T_SEQ - 1) h2last[u] = h;
      }
      if (c == 0) {
        __hip_atomic_fetch_add(cnt2 + (size_t)ci * 64, 1u,
                               __ATOMIC_RELEASE, __HIP_MEMORY_SCOPE_AGENT);
        if (lwg == 0 && wv == 0) ast32(prog, (uint32)(t + 1));
      }
    }
  }
}

// ---------------- tiny MLP head ----------------
extern "C" __global__ void __launch_bounds__(256)
head_fc(const float* __restrict__ W, const float* __restrict__ b,
        const float* __restrict__ xin, float* __restrict__ y, int n_in)
{
  __shared__ float sred[256];
  const int i = blockIdx.x;
  float p = 0.0f;
  for (int k = threadIdx.x; k < n_in; k += 256)
    p = fmaf(W[(size_t)i * n_in + k], xin[k], p);
  sred[threadIdx.x] = p;
  __syncthreads();
  for (int s = 128; s > 0; s >>= 1) {
    if (threadIdx.x < s) sred[threadIdx.x] += sred[threadIdx.x + s];
    __syncthreads();
  }
  if (threadIdx.x == 0) y[i] = fmaxf(sred[0] + b[i], 0.0f);
}

extern "C" __global__ void __launch_bounds__(64)
head_out(const float* __restrict__ W2, const float* __restrict__ b2,
         const float* __restrict__ y1, float* __restrict__ out)
{
  const int l = threadIdx.x;
  float p0 = 0.0f, p1 = 0.0f, p2 = 0.0f;
  for (int k = l; k < 512; k += 64) {
    float v = y1[k];
    p0 = fmaf(W2[k],        v, p0);
    p1 = fmaf(W2[512 + k],  v, p1);
    p2 = fmaf(W2[1024 + k], v, p2);
  }
  #pragma unroll
  for (int m = 1; m < 64; m <<= 1) {
    p0 += __shfl_xor(p0, m);
    p1 += __shfl_xor(p1, m);
    p2 += __shfl_xor(p2, m);
  }
  if (l == 0) {
    float z0 = p0 + b2[0], z1 = p1 + b2[1], z2 = p2 + b2[2];
    float mx = fmaxf(z0, fmaxf(z1, z2));
    float lse = mx + logf(expf(z0 - mx) + expf(z1 - mx) + expf(z2 - mx));
    out[0] = z0 - lse; out[1] = z1 - lse; out[2] = z2 - lse;
  }
}

// ---------------- host ----------------
extern "C" void kernel_launch(void* const* d_in, const int* in_sizes, int n_in,
                              void* d_out, int out_size, void* d_ws, size_t ws_size,
                              hipStream_t stream)
{
  (void)in_sizes; (void)n_in; (void)out_size; (void)ws_size;
  const float* quote = (const float*)d_in[0];
  const float* Wih0  = (const float*)d_in[1];
  const float* Whh0  = (const float*)d_in[2];
  const float* bih0  = (const float*)d_in[3];
  const float* bhh0  = (const float*)d_in[4];
  const float* Wih1  = (const float*)d_in[5];
  const float* Whh1  = (const float*)d_in[6];
  const float* bih1  = (const float*)d_in[7];
  const float* bhh1  = (const float*)d_in[8];
  const float* W0    = (const float*)d_in[9];
  const float* b0    = (const float*)d_in[10];
  const float* W1    = (const float*)d_in[11];
  const float* b1    = (const float*)d_in[12];
  const float* W2    = (const float*)d_in[13];
  const float* b2    = (const float*)d_in[14];

  char* ws = (char*)d_ws;
  uint64* h1r    = (uint64*)(ws + 0);          // [16][1024] tagged fp32 (128 KB)
  uint64* h2r    = (uint64*)(ws + 131072);     // [4][1024]  tagged fp32 (32 KB)
  uint32* cnt1   = (uint32*)(ws + 163840);     // 32 sub-counters x 256B
  uint32* cnt2   = (uint32*)(ws + 172032);     // 32 sub-counters x 256B
  uint32* prog   = (uint32*)(ws + 180224);     // L1 progress watermark
  float*  h2last = (float*)(ws + 180352);      // 1024 f32
  float*  y0     = (float*)(ws + 184448);      // 512 f32
  float*  y1     = (float*)(ws + 186496);      // 512 f32

  hipMemsetAsync(ws, 0, 180352, stream);       // rings + counters + prog

  hipFuncSetAttribute((const void*)lstm_persistent,
                      hipFuncAttributeMaxDynamicSharedMemorySize, LDS_BYTES);

  void* args[] = { (void*)&quote, (void*)&Wih0, (void*)&Whh0, (void*)&bih0, (void*)&bhh0,
                   (void*)&Wih1, (void*)&Whh1, (void*)&bih1, (void*)&bhh1,
                   (void*)&h1r, (void*)&h2r, (void*)&cnt1, (void*)&cnt2,
                   (void*)&prog, (void*)&h2last };
  hipLaunchCooperativeKernel((const void*)lstm_persistent, dim3(256), dim3(256),
                             args, (uint32)LDS_BYTES, stream);

  head_fc<<<512, 256, 0, stream>>>(W0, b0, h2last, y0, 1024);
  head_fc<<<512, 256, 0, stream>>>(W1, b1, y0, y1, 512);
  head_out<<<1, 64, 0, stream>>>(W2, b2, y1, (float*)d_out);
}